// Round 1
// baseline (350.132 us; speedup 1.0000x reference)
//
#include <hip/hip_runtime.h>
#include <math.h>

#define ROWS 32768
#define COLS 1024
#define HEADSZ 1030      // COLS + 1 + 1 + 3 + 1
#define NPARAMS 4108     // 2*HEADSZ + 2*COLS
#define NB_G 512         // blocks for the fused write/read pass

__device__ __forceinline__ float softplusf(float x) {
    return fmaxf(x, 0.f) + log1pf(expf(-fabsf(x)));
}
__device__ __forceinline__ float sigmoidf(float x) {
    return 1.f / (1.f + expf(-x));
}
__device__ __forceinline__ float waveReduceSum(float v) {
#pragma unroll
    for (int off = 32; off > 0; off >>= 1) v += __shfl_xor(v, off, 64);
    return v;
}

// ---- kA: h = Wc @ concat(x, read_prev) + bc  (1024 outputs, dot over 1280)
__global__ __launch_bounds__(256) void kA(const float* __restrict__ x,
                                          const float* __restrict__ rp,
                                          const float* __restrict__ Wc,
                                          const float* __restrict__ bc,
                                          float* __restrict__ h) {
    __shared__ float xc[1280];
    for (int i = threadIdx.x; i < 1280; i += 256)
        xc[i] = (i < 256) ? x[i] : rp[i - 256];
    __syncthreads();
    int wave = threadIdx.x >> 6, lane = threadIdx.x & 63;
    int o = blockIdx.x * 4 + wave;  // 256 blocks * 4 waves = 1024
    const float4* Wr = (const float4*)(Wc + (size_t)o * 1280);
    float acc = 0.f;
#pragma unroll
    for (int j = 0; j < 5; j++) {
        float4 w = Wr[lane + 64 * j];
        float4 v = *(const float4*)(xc + lane * 4 + j * 256);
        acc += w.x * v.x + w.y * v.y + w.z * v.z + w.w * v.w;
    }
    acc = waveReduceSum(acc);
    if (lane == 0) h[o] = acc + bc[o];
}

// ---- kB: p = Wp@h + bp (4108) and saida = sigmoid(Wo@h + bo) (256)
__global__ __launch_bounds__(256) void kB(const float* __restrict__ h,
                                          const float* __restrict__ Wp,
                                          const float* __restrict__ bp,
                                          const float* __restrict__ Wo,
                                          const float* __restrict__ bo,
                                          float* __restrict__ p,
                                          float* __restrict__ saida) {
    __shared__ float hl[1024];
    for (int i = threadIdx.x; i < 1024; i += 256) hl[i] = h[i];
    __syncthreads();
    int wave = threadIdx.x >> 6, lane = threadIdx.x & 63;
    int o = blockIdx.x * 4 + wave;  // 1091 blocks * 4 = 4364 outputs exactly
    if (o >= NPARAMS + 256) return;
    bool isP = o < NPARAMS;
    int oo = isP ? o : o - NPARAMS;
    const float* W = isP ? Wp : Wo;
    const float4* Wr = (const float4*)(W + (size_t)oo * 1024);
    float acc = 0.f;
#pragma unroll
    for (int j = 0; j < 4; j++) {
        float4 w = Wr[lane + 64 * j];
        float4 v = *(const float4*)(hl + lane * 4 + j * 256);
        acc += w.x * v.x + w.y * v.y + w.z * v.z + w.w * v.w;
    }
    acc = waveReduceSum(acc);
    if (lane == 0) {
        if (isP) p[oo] = acc + bp[oo];
        else     saida[oo] = sigmoidf(acc + bo[oo]);
    }
}

// ---- kC: head params: normalized keys, e, a, scalars; zero accumulators
__global__ __launch_bounds__(1024) void kC(const float* __restrict__ p,
                                           float* __restrict__ krn,
                                           float* __restrict__ kwn,
                                           float* __restrict__ evec,
                                           float* __restrict__ avec,
                                           float* __restrict__ scal,
                                           float* __restrict__ sumsE,
                                           float* __restrict__ sumsP) {
    __shared__ float red[1024];
    __shared__ float invr_s, invw_s;
    int t = threadIdx.x;
    float tr = tanhf(p[t]);
    float tw = tanhf(p[HEADSZ + t]);
    red[t] = tr * tr;
    __syncthreads();
    for (int s = 512; s > 0; s >>= 1) {
        if (t < s) red[t] += red[t + s];
        __syncthreads();
    }
    if (t == 0) invr_s = 1.f / fmaxf(sqrtf(red[0]), 1e-12f);
    __syncthreads();
    red[t] = tw * tw;
    __syncthreads();
    for (int s = 512; s > 0; s >>= 1) {
        if (t < s) red[t] += red[t + s];
        __syncthreads();
    }
    if (t == 0) invw_s = 1.f / fmaxf(sqrtf(red[0]), 1e-12f);
    __syncthreads();
    krn[t] = tr * invr_s;
    kwn[t] = tw * invw_s;
    evec[t] = sigmoidf(p[2 * HEADSZ + t]);
    avec[t] = tanhf(p[2 * HEADSZ + COLS + t]);
    if (t < 2) {
        int base = t * HEADSZ + COLS;  // 1024 (read) / 2054 (write)
        float beta = softplusf(p[base]);
        float g = sigmoidf(p[base + 1]);
        float s0 = p[base + 2], s1 = p[base + 3], s2 = p[base + 4];
        float mx = fmaxf(s0, fmaxf(s1, s2));
        float e0 = expf(s0 - mx), e1 = expf(s1 - mx), e2 = expf(s2 - mx);
        float inv = 1.f / (e0 + e1 + e2);
        float gamma = softplusf(p[base + 5]) + 1.f;
        float* sc = scal + t * 6;
        sc[0] = beta; sc[1] = g;
        sc[2] = e0 * inv; sc[3] = e1 * inv; sc[4] = e2 * inv;
        sc[5] = gamma;
        sumsE[t] = 0.f;
        sumsP[t] = 0.f;
    }
}

// ---- kD: one pass over memoria: sims for both heads + row norms -> exp + sums
__global__ __launch_bounds__(256) void kD(const float* __restrict__ mem,
                                          const float* __restrict__ krn,
                                          const float* __restrict__ kwn,
                                          const float* __restrict__ scal,
                                          float* __restrict__ er,
                                          float* __restrict__ ew,
                                          float* __restrict__ sumsE) {
    int wave = threadIdx.x >> 6, lane = threadIdx.x & 63;
    int gw = blockIdx.x * 4 + wave;
    int nw = gridDim.x * 4;
    float beta_r = scal[0], beta_w = scal[6];
    float4 kr4[4], kw4[4];
#pragma unroll
    for (int j = 0; j < 4; j++) {
        kr4[j] = *(const float4*)(krn + lane * 4 + j * 256);
        kw4[j] = *(const float4*)(kwn + lane * 4 + j * 256);
    }
    float lr = 0.f, lw = 0.f;
    for (int r = gw; r < ROWS; r += nw) {
        const float4* row = (const float4*)(mem + (size_t)r * COLS);
        float ar = 0.f, aw = 0.f, an = 0.f;
#pragma unroll
        for (int j = 0; j < 4; j++) {
            float4 m = row[lane + 64 * j];
            ar += m.x * kr4[j].x + m.y * kr4[j].y + m.z * kr4[j].z + m.w * kr4[j].w;
            aw += m.x * kw4[j].x + m.y * kw4[j].y + m.z * kw4[j].z + m.w * kw4[j].w;
            an += m.x * m.x + m.y * m.y + m.z * m.z + m.w * m.w;
        }
#pragma unroll
        for (int off = 32; off > 0; off >>= 1) {
            ar += __shfl_xor(ar, off, 64);
            aw += __shfl_xor(aw, off, 64);
            an += __shfl_xor(an, off, 64);
        }
        if (lane == 0) {
            float inv = 1.f / fmaxf(sqrtf(an), 1e-12f);
            // softmax shift by beta (valid: max(beta*sim) <= beta); exact math
            float vr = expf(beta_r * (ar * inv - 1.f));
            float vw = expf(beta_w * (aw * inv - 1.f));
            er[r] = vr;
            ew[r] = vw;
            lr += vr;
            lw += vw;
        }
    }
    __shared__ float ls[8];
    if (lane == 0) { ls[wave] = lr; ls[4 + wave] = lw; }
    __syncthreads();
    if (threadIdx.x == 0) {
        atomicAdd(&sumsE[0], ls[0] + ls[1] + ls[2] + ls[3]);
        atomicAdd(&sumsE[1], ls[4] + ls[5] + ls[6] + ls[7]);
    }
}

// ---- kE: gate + circular shift + sharpen (pow), partial sums of pow
__global__ __launch_bounds__(256) void kE(const float* __restrict__ er,
                                          const float* __restrict__ ew,
                                          const float* __restrict__ wrp,
                                          const float* __restrict__ wwp,
                                          const float* __restrict__ scal,
                                          const float* __restrict__ sumsE,
                                          float* __restrict__ powr,
                                          float* __restrict__ poww,
                                          float* __restrict__ sumsP) {
    int head = blockIdx.y;
    const float* ee = head ? ew : er;
    const float* wp = head ? wwp : wrp;
    const float* sc = scal + head * 6;
    float g = sc[1], s0 = sc[2], s1 = sc[3], s2 = sc[4], gamma = sc[5];
    float invS = 1.f / sumsE[head];
    int i = blockIdx.x * 256 + threadIdx.x;
    int im = (i - 1) & (ROWS - 1), ip = (i + 1) & (ROWS - 1);
    float wgm = g * ee[im] * invS + (1.f - g) * wp[im];
    float wg0 = g * ee[i] * invS + (1.f - g) * wp[i];
    float wgp = g * ee[ip] * invS + (1.f - g) * wp[ip];
    float wt = s0 * wgm + s1 * wg0 + s2 * wgp;  // roll(+1)*s0 + w*s1 + roll(-1)*s2
    float pw = powf(wt, gamma);
    (head ? poww : powr)[i] = pw;
    __shared__ float red[256];
    red[threadIdx.x] = pw;
    __syncthreads();
    for (int s = 128; s > 0; s >>= 1) {
        if (threadIdx.x < s) red[threadIdx.x] += red[threadIdx.x + s];
        __syncthreads();
    }
    if (threadIdx.x == 0) atomicAdd(&sumsP[head], red[0]);
}

// ---- kF: write normalized w_read / w_write outputs
__global__ __launch_bounds__(256) void kF(const float* __restrict__ powr,
                                          const float* __restrict__ poww,
                                          const float* __restrict__ sumsP,
                                          float* __restrict__ owr,
                                          float* __restrict__ oww) {
    int i = blockIdx.x * 256 + threadIdx.x;  // 0..65535
    int head = i >> 15, idx = i & (ROWS - 1);
    float inv = 1.f / (sumsP[head] + 1e-8f);
    float v = (head ? poww : powr)[idx] * inv;
    (head ? oww : owr)[idx] = v;
}

// ---- kG: fused final pass: mem_new = m*(1-ww*e)+ww*a, read_vec partials
__global__ __launch_bounds__(256) void kG(const float* __restrict__ mem,
                                          const float* __restrict__ powr,
                                          const float* __restrict__ poww,
                                          const float* __restrict__ sumsP,
                                          const float* __restrict__ evec,
                                          const float* __restrict__ avec,
                                          float* __restrict__ memnew,
                                          float* __restrict__ partials) {
    int t = threadIdx.x;  // 256 threads, each owns 4 fixed columns
    float4 e4 = ((const float4*)evec)[t];
    float4 a4 = ((const float4*)avec)[t];
    float invSr = 1.f / (sumsP[0] + 1e-8f);
    float invSw = 1.f / (sumsP[1] + 1e-8f);
    float4 acc = make_float4(0.f, 0.f, 0.f, 0.f);
    for (int r = blockIdx.x; r < ROWS; r += NB_G) {
        float wr = powr[r] * invSr;
        float ww = poww[r] * invSw;
        float4 m = ((const float4*)(mem + (size_t)r * COLS))[t];
        float4 o;
        o.x = m.x * (1.f - ww * e4.x) + ww * a4.x;
        o.y = m.y * (1.f - ww * e4.y) + ww * a4.y;
        o.z = m.z * (1.f - ww * e4.z) + ww * a4.z;
        o.w = m.w * (1.f - ww * e4.w) + ww * a4.w;
        ((float4*)(memnew + (size_t)r * COLS))[t] = o;
        acc.x += wr * m.x;
        acc.y += wr * m.y;
        acc.z += wr * m.z;
        acc.w += wr * m.w;
    }
    ((float4*)(partials + (size_t)blockIdx.x * COLS))[t] = acc;
}

// ---- kH: reduce per-block read_vec partials
__global__ __launch_bounds__(256) void kH(const float* __restrict__ partials,
                                          float* __restrict__ readv) {
    int c = blockIdx.x * 256 + threadIdx.x;  // 0..1023
    float s = 0.f;
    for (int b = 0; b < NB_G; b++) s += partials[(size_t)b * COLS + c];
    readv[c] = s;
}

extern "C" void kernel_launch(void* const* d_in, const int* in_sizes, int n_in,
                              void* d_out, int out_size, void* d_ws, size_t ws_size,
                              hipStream_t stream) {
    const float* x   = (const float*)d_in[0];
    const float* mem = (const float*)d_in[1];
    const float* Wc  = (const float*)d_in[2];
    const float* bc  = (const float*)d_in[3];
    const float* Wp  = (const float*)d_in[4];
    const float* bp  = (const float*)d_in[5];
    const float* Wo  = (const float*)d_in[6];
    const float* bo  = (const float*)d_in[7];
    const float* rp  = (const float*)d_in[8];
    const float* wrp = (const float*)d_in[9];
    const float* wwp = (const float*)d_in[10];

    float* out    = (float*)d_out;
    float* saida  = out;                                // 256
    float* memnew = out + 256;                          // ROWS*COLS
    float* readv  = out + 256 + (size_t)ROWS * COLS;    // 1024
    float* owr    = readv + COLS;                       // 32768
    float* oww    = owr + ROWS;                         // 32768

    float* ws    = (float*)d_ws;
    float* h     = ws;            // 1024
    float* p     = ws + 1024;     // 4108 (ends 5132, padded)
    float* krn   = ws + 5136;     // 1024
    float* kwn   = ws + 6160;     // 1024
    float* evec  = ws + 7184;     // 1024
    float* avec  = ws + 8208;     // 1024
    float* scal  = ws + 9232;     // 12
    float* sumsE = ws + 9248;     // 2
    float* sumsP = ws + 9252;     // 2
    float* er    = ws + 9264;     // 32768
    float* ew    = er + ROWS;     // 32768
    float* powr  = ew + ROWS;     // 32768
    float* poww  = powr + ROWS;   // 32768
    float* partials = poww + ROWS;  // NB_G*1024 = 524288 (~2.7 MB total ws)

    kA<<<dim3(256), dim3(256), 0, stream>>>(x, rp, Wc, bc, h);
    kB<<<dim3(1091), dim3(256), 0, stream>>>(h, Wp, bp, Wo, bo, p, saida);
    kC<<<dim3(1), dim3(1024), 0, stream>>>(p, krn, kwn, evec, avec, scal, sumsE, sumsP);
    kD<<<dim3(2048), dim3(256), 0, stream>>>(mem, krn, kwn, scal, er, ew, sumsE);
    kE<<<dim3(128, 2), dim3(256), 0, stream>>>(er, ew, wrp, wwp, scal, sumsE, powr, poww, sumsP);
    kF<<<dim3(256), dim3(256), 0, stream>>>(powr, poww, sumsP, owr, oww);
    kG<<<dim3(NB_G), dim3(256), 0, stream>>>(mem, powr, poww, sumsP, evec, avec, memnew, partials);
    kH<<<dim3(4), dim3(256), 0, stream>>>(partials, readv);
}

// Round 3
// 343.611 us; speedup vs baseline: 1.0190x; 1.0190x over previous
//
#include <hip/hip_runtime.h>
#include <math.h>

#define ROWS 32768
#define COLS 1024
#define HEADSZ 1030      // COLS + 1 + 1 + 3 + 1
#define NPARAMS 4108     // 2*HEADSZ + 2*COLS
#define NB_G 1024        // blocks for the fused write/read pass (32 rows each)

typedef float vfloat4 __attribute__((ext_vector_type(4)));

__device__ __forceinline__ float softplusf(float x) {
    return fmaxf(x, 0.f) + log1pf(expf(-fabsf(x)));
}
__device__ __forceinline__ float sigmoidf(float x) {
    return 1.f / (1.f + expf(-x));
}
__device__ __forceinline__ float waveReduceSum(float v) {
#pragma unroll
    for (int off = 32; off > 0; off >>= 1) v += __shfl_xor(v, off, 64);
    return v;
}

// ---- kA: h = Wc @ concat(x, read_prev) + bc  (1024 outputs, dot over 1280)
__global__ __launch_bounds__(256) void kA(const float* __restrict__ x,
                                          const float* __restrict__ rp,
                                          const float* __restrict__ Wc,
                                          const float* __restrict__ bc,
                                          float* __restrict__ h) {
    __shared__ float xc[1280];
    for (int i = threadIdx.x; i < 1280; i += 256)
        xc[i] = (i < 256) ? x[i] : rp[i - 256];
    __syncthreads();
    int wave = threadIdx.x >> 6, lane = threadIdx.x & 63;
    int o = blockIdx.x * 4 + wave;  // 256 blocks * 4 waves = 1024
    const float4* Wr = (const float4*)(Wc + (size_t)o * 1280);
    float acc = 0.f;
#pragma unroll
    for (int j = 0; j < 5; j++) {
        float4 w = Wr[lane + 64 * j];
        float4 v = *(const float4*)(xc + lane * 4 + j * 256);
        acc += w.x * v.x + w.y * v.y + w.z * v.z + w.w * v.w;
    }
    acc = waveReduceSum(acc);
    if (lane == 0) h[o] = acc + bc[o];
}

// ---- kB: p = Wp@h + bp (4108) and saida = sigmoid(Wo@h + bo) (256)
__global__ __launch_bounds__(256) void kB(const float* __restrict__ h,
                                          const float* __restrict__ Wp,
                                          const float* __restrict__ bp,
                                          const float* __restrict__ Wo,
                                          const float* __restrict__ bo,
                                          float* __restrict__ p,
                                          float* __restrict__ saida) {
    __shared__ float hl[1024];
    for (int i = threadIdx.x; i < 1024; i += 256) hl[i] = h[i];
    __syncthreads();
    int wave = threadIdx.x >> 6, lane = threadIdx.x & 63;
    int o = blockIdx.x * 4 + wave;  // 1091 blocks * 4 = 4364 outputs exactly
    if (o >= NPARAMS + 256) return;
    bool isP = o < NPARAMS;
    int oo = isP ? o : o - NPARAMS;
    const float* W = isP ? Wp : Wo;
    const float4* Wr = (const float4*)(W + (size_t)oo * 1024);
    float acc = 0.f;
#pragma unroll
    for (int j = 0; j < 4; j++) {
        float4 w = Wr[lane + 64 * j];
        float4 v = *(const float4*)(hl + lane * 4 + j * 256);
        acc += w.x * v.x + w.y * v.y + w.z * v.z + w.w * v.w;
    }
    acc = waveReduceSum(acc);
    if (lane == 0) {
        if (isP) p[oo] = acc + bp[oo];
        else     saida[oo] = sigmoidf(acc + bo[oo]);
    }
}

// ---- kC: head params: normalized keys, e, a, scalars; zero accumulators
__global__ __launch_bounds__(1024) void kC(const float* __restrict__ p,
                                           float* __restrict__ krn,
                                           float* __restrict__ kwn,
                                           float* __restrict__ evec,
                                           float* __restrict__ avec,
                                           float* __restrict__ scal,
                                           float* __restrict__ sumsE,
                                           float* __restrict__ sumsP) {
    __shared__ float red[1024];
    __shared__ float invr_s, invw_s;
    int t = threadIdx.x;
    float tr = tanhf(p[t]);
    float tw = tanhf(p[HEADSZ + t]);
    red[t] = tr * tr;
    __syncthreads();
    for (int s = 512; s > 0; s >>= 1) {
        if (t < s) red[t] += red[t + s];
        __syncthreads();
    }
    if (t == 0) invr_s = 1.f / fmaxf(sqrtf(red[0]), 1e-12f);
    __syncthreads();
    red[t] = tw * tw;
    __syncthreads();
    for (int s = 512; s > 0; s >>= 1) {
        if (t < s) red[t] += red[t + s];
        __syncthreads();
    }
    if (t == 0) invw_s = 1.f / fmaxf(sqrtf(red[0]), 1e-12f);
    __syncthreads();
    krn[t] = tr * invr_s;
    kwn[t] = tw * invw_s;
    evec[t] = sigmoidf(p[2 * HEADSZ + t]);
    avec[t] = tanhf(p[2 * HEADSZ + COLS + t]);
    if (t < 2) {
        int base = t * HEADSZ + COLS;  // 1024 (read) / 2054 (write)
        float beta = softplusf(p[base]);
        float g = sigmoidf(p[base + 1]);
        float s0 = p[base + 2], s1 = p[base + 3], s2 = p[base + 4];
        float mx = fmaxf(s0, fmaxf(s1, s2));
        float e0 = expf(s0 - mx), e1 = expf(s1 - mx), e2 = expf(s2 - mx);
        float inv = 1.f / (e0 + e1 + e2);
        float gamma = softplusf(p[base + 5]) + 1.f;
        float* sc = scal + t * 6;
        sc[0] = beta; sc[1] = g;
        sc[2] = e0 * inv; sc[3] = e1 * inv; sc[4] = e2 * inv;
        sc[5] = gamma;
        sumsE[t] = 0.f;
        sumsP[t] = 0.f;
    }
}

// ---- kD: one pass over memoria: sims for both heads + row norms -> exp + sums
// contiguous 4-row chunk per wave for streaming locality
__global__ __launch_bounds__(256) void kD(const float* __restrict__ mem,
                                          const float* __restrict__ krn,
                                          const float* __restrict__ kwn,
                                          const float* __restrict__ scal,
                                          float* __restrict__ er,
                                          float* __restrict__ ew,
                                          float* __restrict__ sumsE) {
    int wave = threadIdx.x >> 6, lane = threadIdx.x & 63;
    int wid = blockIdx.x * 4 + wave;       // 0..8191
    int r0 = wid * 4;                      // contiguous 4 rows
    float beta_r = scal[0], beta_w = scal[6];
    float4 kr4[4], kw4[4];
#pragma unroll
    for (int j = 0; j < 4; j++) {
        kr4[j] = *(const float4*)(krn + lane * 4 + j * 256);
        kw4[j] = *(const float4*)(kwn + lane * 4 + j * 256);
    }
    float lr = 0.f, lw = 0.f;
#pragma unroll
    for (int rr = 0; rr < 4; rr++) {
        int r = r0 + rr;
        const float4* row = (const float4*)(mem + (size_t)r * COLS);
        float ar = 0.f, aw = 0.f, an = 0.f;
#pragma unroll
        for (int j = 0; j < 4; j++) {
            float4 m = row[lane + 64 * j];
            ar += m.x * kr4[j].x + m.y * kr4[j].y + m.z * kr4[j].z + m.w * kr4[j].w;
            aw += m.x * kw4[j].x + m.y * kw4[j].y + m.z * kw4[j].z + m.w * kw4[j].w;
            an += m.x * m.x + m.y * m.y + m.z * m.z + m.w * m.w;
        }
#pragma unroll
        for (int off = 32; off > 0; off >>= 1) {
            ar += __shfl_xor(ar, off, 64);
            aw += __shfl_xor(aw, off, 64);
            an += __shfl_xor(an, off, 64);
        }
        if (lane == 0) {
            float inv = 1.f / fmaxf(sqrtf(an), 1e-12f);
            // softmax shift by beta (valid: max(beta*sim) <= beta); exact math
            float vr = expf(beta_r * (ar * inv - 1.f));
            float vw = expf(beta_w * (aw * inv - 1.f));
            er[r] = vr;
            ew[r] = vw;
            lr += vr;
            lw += vw;
        }
    }
    __shared__ float ls[8];
    if (lane == 0) { ls[wave] = lr; ls[4 + wave] = lw; }
    __syncthreads();
    if (threadIdx.x == 0) {
        atomicAdd(&sumsE[0], ls[0] + ls[1] + ls[2] + ls[3]);
        atomicAdd(&sumsE[1], ls[4] + ls[5] + ls[6] + ls[7]);
    }
}

// ---- kE: gate + circular shift + sharpen (pow), partial sums of pow
__global__ __launch_bounds__(256) void kE(const float* __restrict__ er,
                                          const float* __restrict__ ew,
                                          const float* __restrict__ wrp,
                                          const float* __restrict__ wwp,
                                          const float* __restrict__ scal,
                                          const float* __restrict__ sumsE,
                                          float* __restrict__ powr,
                                          float* __restrict__ poww,
                                          float* __restrict__ sumsP) {
    int head = blockIdx.y;
    const float* ee = head ? ew : er;
    const float* wp = head ? wwp : wrp;
    const float* sc = scal + head * 6;
    float g = sc[1], s0 = sc[2], s1 = sc[3], s2 = sc[4], gamma = sc[5];
    float invS = 1.f / sumsE[head];
    int i = blockIdx.x * 256 + threadIdx.x;
    int im = (i - 1) & (ROWS - 1), ip = (i + 1) & (ROWS - 1);
    float wgm = g * ee[im] * invS + (1.f - g) * wp[im];
    float wg0 = g * ee[i] * invS + (1.f - g) * wp[i];
    float wgp = g * ee[ip] * invS + (1.f - g) * wp[ip];
    float wt = s0 * wgm + s1 * wg0 + s2 * wgp;  // roll(+1)*s0 + w*s1 + roll(-1)*s2
    float pw = powf(wt, gamma);
    (head ? poww : powr)[i] = pw;
    __shared__ float red[256];
    red[threadIdx.x] = pw;
    __syncthreads();
    for (int s = 128; s > 0; s >>= 1) {
        if (threadIdx.x < s) red[threadIdx.x] += red[threadIdx.x + s];
        __syncthreads();
    }
    if (threadIdx.x == 0) atomicAdd(&sumsP[head], red[0]);
}

// ---- kG: fused final pass over contiguous 32-row chunks:
//   mem_new = m*(1-ww*e)+ww*a  (nontemporal store — never re-read)
//   read_vec block partials; also writes normalized w_read/w_write outputs
__global__ __launch_bounds__(256) void kG(const float* __restrict__ mem,
                                          const float* __restrict__ powr,
                                          const float* __restrict__ poww,
                                          const float* __restrict__ sumsP,
                                          const float* __restrict__ evec,
                                          const float* __restrict__ avec,
                                          float* __restrict__ memnew,
                                          float* __restrict__ partials,
                                          float* __restrict__ owr,
                                          float* __restrict__ oww) {
    int t = threadIdx.x;  // 256 threads, each owns 4 fixed columns
    int r0 = blockIdx.x * 32;
    __shared__ float swr[32], sww[32];
    if (t < 32)      swr[t] = powr[r0 + t] * (1.f / (sumsP[0] + 1e-8f));
    else if (t < 64) sww[t - 32] = poww[r0 + t - 32] * (1.f / (sumsP[1] + 1e-8f));
    __syncthreads();
    if (t < 32)      owr[r0 + t] = swr[t];
    else if (t < 64) oww[r0 + t - 32] = sww[t - 32];
    float4 e4 = ((const float4*)evec)[t];
    float4 a4 = ((const float4*)avec)[t];
    float4 acc = make_float4(0.f, 0.f, 0.f, 0.f);
#pragma unroll 4
    for (int rr = 0; rr < 32; rr++) {
        int r = r0 + rr;
        float wr = swr[rr];
        float ww = sww[rr];
        float4 m = ((const float4*)(mem + (size_t)r * COLS))[t];
        vfloat4 o;
        o.x = m.x * (1.f - ww * e4.x) + ww * a4.x;
        o.y = m.y * (1.f - ww * e4.y) + ww * a4.y;
        o.z = m.z * (1.f - ww * e4.z) + ww * a4.z;
        o.w = m.w * (1.f - ww * e4.w) + ww * a4.w;
        __builtin_nontemporal_store(o, ((vfloat4*)(memnew + (size_t)r * COLS)) + t);
        acc.x += wr * m.x;
        acc.y += wr * m.y;
        acc.z += wr * m.z;
        acc.w += wr * m.w;
    }
    ((float4*)(partials + (size_t)blockIdx.x * COLS))[t] = acc;
}

// ---- kH: reduce per-block read_vec partials; one wave per column
__global__ __launch_bounds__(64) void kH(const float* __restrict__ partials,
                                         float* __restrict__ readv) {
    int c = blockIdx.x;          // 0..1023
    int lane = threadIdx.x;      // 0..63
    float s = 0.f;
#pragma unroll
    for (int k = 0; k < NB_G / 64; k++)
        s += partials[(size_t)(lane + 64 * k) * COLS + c];
    s = waveReduceSum(s);
    if (lane == 0) readv[c] = s;
}

extern "C" void kernel_launch(void* const* d_in, const int* in_sizes, int n_in,
                              void* d_out, int out_size, void* d_ws, size_t ws_size,
                              hipStream_t stream) {
    const float* x   = (const float*)d_in[0];
    const float* mem = (const float*)d_in[1];
    const float* Wc  = (const float*)d_in[2];
    const float* bc  = (const float*)d_in[3];
    const float* Wp  = (const float*)d_in[4];
    const float* bp  = (const float*)d_in[5];
    const float* Wo  = (const float*)d_in[6];
    const float* bo  = (const float*)d_in[7];
    const float* rp  = (const float*)d_in[8];
    const float* wrp = (const float*)d_in[9];
    const float* wwp = (const float*)d_in[10];

    float* out    = (float*)d_out;
    float* saida  = out;                                // 256
    float* memnew = out + 256;                          // ROWS*COLS
    float* readv  = out + 256 + (size_t)ROWS * COLS;    // 1024
    float* owr    = readv + COLS;                       // 32768
    float* oww    = owr + ROWS;                         // 32768

    float* ws    = (float*)d_ws;
    float* h     = ws;            // 1024
    float* p     = ws + 1024;     // 4108 (ends 5132, padded)
    float* krn   = ws + 5136;     // 1024
    float* kwn   = ws + 6160;     // 1024
    float* evec  = ws + 7184;     // 1024
    float* avec  = ws + 8208;     // 1024
    float* scal  = ws + 9232;     // 12
    float* sumsE = ws + 9248;     // 2
    float* sumsP = ws + 9252;     // 2
    float* er    = ws + 9264;     // 32768
    float* ew    = er + ROWS;     // 32768
    float* powr  = ew + ROWS;     // 32768
    float* poww  = powr + ROWS;   // 32768
    float* partials = poww + ROWS;  // NB_G*1024 = 1M floats (4 MB)

    kA<<<dim3(256), dim3(256), 0, stream>>>(x, rp, Wc, bc, h);
    kB<<<dim3(1091), dim3(256), 0, stream>>>(h, Wp, bp, Wo, bo, p, saida);
    kC<<<dim3(1), dim3(1024), 0, stream>>>(p, krn, kwn, evec, avec, scal, sumsE, sumsP);
    kD<<<dim3(2048), dim3(256), 0, stream>>>(mem, krn, kwn, scal, er, ew, sumsE);
    kE<<<dim3(128, 2), dim3(256), 0, stream>>>(er, ew, wrp, wwp, scal, sumsE, powr, poww, sumsP);
    kG<<<dim3(NB_G), dim3(256), 0, stream>>>(mem, powr, poww, sumsP, evec, avec, memnew, partials, owr, oww);
    kH<<<dim3(1024), dim3(64), 0, stream>>>(partials, readv);
}

// Round 4
// 314.172 us; speedup vs baseline: 1.1145x; 1.0937x over previous
//
#include <hip/hip_runtime.h>
#include <math.h>

#define ROWS 32768
#define COLS 1024
#define HEADSZ 1030      // COLS + 1 + 1 + 3 + 1
#define NPARAMS 4108     // 2*HEADSZ + 2*COLS
#define NB_G 1024        // blocks for the fused write/read pass (32 rows each)
// atomic-contention spreading: slots are cache-line padded (stride 16 floats)
#define SLOT_E 32        // kD: 2048 blocks -> 64 adds per slot
#define SLOT_P 16        // kE: 256 blocks -> 16 adds per slot

typedef float vfloat4 __attribute__((ext_vector_type(4)));

__device__ __forceinline__ float softplusf(float x) {
    return fmaxf(x, 0.f) + log1pf(expf(-fabsf(x)));
}
__device__ __forceinline__ float sigmoidf(float x) {
    return 1.f / (1.f + expf(-x));
}
__device__ __forceinline__ float waveReduceSum(float v) {
#pragma unroll
    for (int off = 32; off > 0; off >>= 1) v += __shfl_xor(v, off, 64);
    return v;
}

// ---- kA: h = Wc @ concat(x, read_prev) + bc  (1024 outputs, dot over 1280)
__global__ __launch_bounds__(256) void kA(const float* __restrict__ x,
                                          const float* __restrict__ rp,
                                          const float* __restrict__ Wc,
                                          const float* __restrict__ bc,
                                          float* __restrict__ h) {
    __shared__ float xc[1280];
    for (int i = threadIdx.x; i < 1280; i += 256)
        xc[i] = (i < 256) ? x[i] : rp[i - 256];
    __syncthreads();
    int wave = threadIdx.x >> 6, lane = threadIdx.x & 63;
    int o = blockIdx.x * 4 + wave;  // 256 blocks * 4 waves = 1024
    const float4* Wr = (const float4*)(Wc + (size_t)o * 1280);
    float acc = 0.f;
#pragma unroll
    for (int j = 0; j < 5; j++) {
        float4 w = Wr[lane + 64 * j];
        float4 v = *(const float4*)(xc + lane * 4 + j * 256);
        acc += w.x * v.x + w.y * v.y + w.z * v.z + w.w * v.w;
    }
    acc = waveReduceSum(acc);
    if (lane == 0) h[o] = acc + bc[o];
}

// ---- kB: p = Wp@h + bp (4108) and saida = sigmoid(Wo@h + bo) (256)
__global__ __launch_bounds__(256) void kB(const float* __restrict__ h,
                                          const float* __restrict__ Wp,
                                          const float* __restrict__ bp,
                                          const float* __restrict__ Wo,
                                          const float* __restrict__ bo,
                                          float* __restrict__ p,
                                          float* __restrict__ saida) {
    __shared__ float hl[1024];
    for (int i = threadIdx.x; i < 1024; i += 256) hl[i] = h[i];
    __syncthreads();
    int wave = threadIdx.x >> 6, lane = threadIdx.x & 63;
    int o = blockIdx.x * 4 + wave;  // 1091 blocks * 4 = 4364 outputs exactly
    if (o >= NPARAMS + 256) return;
    bool isP = o < NPARAMS;
    int oo = isP ? o : o - NPARAMS;
    const float* W = isP ? Wp : Wo;
    const float4* Wr = (const float4*)(W + (size_t)oo * 1024);
    float acc = 0.f;
#pragma unroll
    for (int j = 0; j < 4; j++) {
        float4 w = Wr[lane + 64 * j];
        float4 v = *(const float4*)(hl + lane * 4 + j * 256);
        acc += w.x * v.x + w.y * v.y + w.z * v.z + w.w * v.w;
    }
    acc = waveReduceSum(acc);
    if (lane == 0) {
        if (isP) p[oo] = acc + bp[oo];
        else     saida[oo] = sigmoidf(acc + bo[oo]);
    }
}

// ---- kC: head params: normalized keys, e, a, scalars; zero slotted accumulators
__global__ __launch_bounds__(1024) void kC(const float* __restrict__ p,
                                           float* __restrict__ krn,
                                           float* __restrict__ kwn,
                                           float* __restrict__ evec,
                                           float* __restrict__ avec,
                                           float* __restrict__ scal,
                                           float* __restrict__ sumsEs,
                                           float* __restrict__ sumsPs) {
    __shared__ float red[1024];
    __shared__ float invr_s, invw_s;
    int t = threadIdx.x;
    // zero the slotted accumulators (re-poisoned to 0xAA before every launch)
    sumsEs[t] = 0.f;                 // 2*SLOT_E*16 = 1024 floats
    if (t < 2 * SLOT_P * 16) sumsPs[t] = 0.f;  // 512 floats
    float tr = tanhf(p[t]);
    float tw = tanhf(p[HEADSZ + t]);
    red[t] = tr * tr;
    __syncthreads();
    for (int s = 512; s > 0; s >>= 1) {
        if (t < s) red[t] += red[t + s];
        __syncthreads();
    }
    if (t == 0) invr_s = 1.f / fmaxf(sqrtf(red[0]), 1e-12f);
    __syncthreads();
    red[t] = tw * tw;
    __syncthreads();
    for (int s = 512; s > 0; s >>= 1) {
        if (t < s) red[t] += red[t + s];
        __syncthreads();
    }
    if (t == 0) invw_s = 1.f / fmaxf(sqrtf(red[0]), 1e-12f);
    __syncthreads();
    krn[t] = tr * invr_s;
    kwn[t] = tw * invw_s;
    evec[t] = sigmoidf(p[2 * HEADSZ + t]);
    avec[t] = tanhf(p[2 * HEADSZ + COLS + t]);
    if (t < 2) {
        int base = t * HEADSZ + COLS;  // 1024 (read) / 2054 (write)
        float beta = softplusf(p[base]);
        float g = sigmoidf(p[base + 1]);
        float s0 = p[base + 2], s1 = p[base + 3], s2 = p[base + 4];
        float mx = fmaxf(s0, fmaxf(s1, s2));
        float e0 = expf(s0 - mx), e1 = expf(s1 - mx), e2 = expf(s2 - mx);
        float inv = 1.f / (e0 + e1 + e2);
        float gamma = softplusf(p[base + 5]) + 1.f;
        float* sc = scal + t * 6;
        sc[0] = beta; sc[1] = g;
        sc[2] = e0 * inv; sc[3] = e1 * inv; sc[4] = e2 * inv;
        sc[5] = gamma;
    }
}

// ---- kD: one pass over memoria: sims for both heads + row norms -> exp + sums
// contiguous 4-row chunk per wave; per-block sums scattered over SLOT_E slots
__global__ __launch_bounds__(256) void kD(const float* __restrict__ mem,
                                          const float* __restrict__ krn,
                                          const float* __restrict__ kwn,
                                          const float* __restrict__ scal,
                                          float* __restrict__ er,
                                          float* __restrict__ ew,
                                          float* __restrict__ sumsEs) {
    int wave = threadIdx.x >> 6, lane = threadIdx.x & 63;
    int wid = blockIdx.x * 4 + wave;       // 0..8191
    int r0 = wid * 4;                      // contiguous 4 rows
    float beta_r = scal[0], beta_w = scal[6];
    float4 kr4[4], kw4[4];
#pragma unroll
    for (int j = 0; j < 4; j++) {
        kr4[j] = *(const float4*)(krn + lane * 4 + j * 256);
        kw4[j] = *(const float4*)(kwn + lane * 4 + j * 256);
    }
    float lr = 0.f, lw = 0.f;
#pragma unroll
    for (int rr = 0; rr < 4; rr++) {
        int r = r0 + rr;
        const float4* row = (const float4*)(mem + (size_t)r * COLS);
        float ar = 0.f, aw = 0.f, an = 0.f;
#pragma unroll
        for (int j = 0; j < 4; j++) {
            float4 m = row[lane + 64 * j];
            ar += m.x * kr4[j].x + m.y * kr4[j].y + m.z * kr4[j].z + m.w * kr4[j].w;
            aw += m.x * kw4[j].x + m.y * kw4[j].y + m.z * kw4[j].z + m.w * kw4[j].w;
            an += m.x * m.x + m.y * m.y + m.z * m.z + m.w * m.w;
        }
#pragma unroll
        for (int off = 32; off > 0; off >>= 1) {
            ar += __shfl_xor(ar, off, 64);
            aw += __shfl_xor(aw, off, 64);
            an += __shfl_xor(an, off, 64);
        }
        if (lane == 0) {
            float inv = 1.f / fmaxf(sqrtf(an), 1e-12f);
            // softmax shift by beta (valid: max(beta*sim) <= beta); exact math
            float vr = expf(beta_r * (ar * inv - 1.f));
            float vw = expf(beta_w * (aw * inv - 1.f));
            er[r] = vr;
            ew[r] = vw;
            lr += vr;
            lw += vw;
        }
    }
    __shared__ float ls[8];
    if (lane == 0) { ls[wave] = lr; ls[4 + wave] = lw; }
    __syncthreads();
    if (threadIdx.x == 0) {
        int slot = blockIdx.x & (SLOT_E - 1);
        atomicAdd(&sumsEs[slot * 16], ls[0] + ls[1] + ls[2] + ls[3]);
        atomicAdd(&sumsEs[(SLOT_E + slot) * 16], ls[4] + ls[5] + ls[6] + ls[7]);
    }
}

// ---- kE: gate + circular shift + sharpen (pow), slotted partial sums of pow
__global__ __launch_bounds__(256) void kE(const float* __restrict__ er,
                                          const float* __restrict__ ew,
                                          const float* __restrict__ wrp,
                                          const float* __restrict__ wwp,
                                          const float* __restrict__ scal,
                                          const float* __restrict__ sumsEs,
                                          float* __restrict__ powr,
                                          float* __restrict__ poww,
                                          float* __restrict__ sumsPs) {
    int head = blockIdx.y;
    const float* ee = head ? ew : er;
    const float* wp = head ? wwp : wrp;
    const float* sc = scal + head * 6;
    float g = sc[1], s0 = sc[2], s1 = sc[3], s2 = sc[4], gamma = sc[5];
    float sE = 0.f;
#pragma unroll
    for (int i = 0; i < SLOT_E; i++) sE += sumsEs[(head * SLOT_E + i) * 16];
    float invS = 1.f / sE;
    int i = blockIdx.x * 256 + threadIdx.x;
    int im = (i - 1) & (ROWS - 1), ip = (i + 1) & (ROWS - 1);
    float wgm = g * ee[im] * invS + (1.f - g) * wp[im];
    float wg0 = g * ee[i] * invS + (1.f - g) * wp[i];
    float wgp = g * ee[ip] * invS + (1.f - g) * wp[ip];
    float wt = s0 * wgm + s1 * wg0 + s2 * wgp;  // roll(+1)*s0 + w*s1 + roll(-1)*s2
    float pw = powf(wt, gamma);
    (head ? poww : powr)[i] = pw;
    __shared__ float red[256];
    red[threadIdx.x] = pw;
    __syncthreads();
    for (int s = 128; s > 0; s >>= 1) {
        if (threadIdx.x < s) red[threadIdx.x] += red[threadIdx.x + s];
        __syncthreads();
    }
    if (threadIdx.x == 0) {
        int slot = blockIdx.x & (SLOT_P - 1);
        atomicAdd(&sumsPs[(head * SLOT_P + slot) * 16], red[0]);
    }
}

// ---- kG: fused final pass over contiguous 32-row chunks:
//   mem_new = m*(1-ww*e)+ww*a  (nontemporal store — never re-read)
//   read_vec block partials; also writes normalized w_read/w_write outputs
__global__ __launch_bounds__(256) void kG(const float* __restrict__ mem,
                                          const float* __restrict__ powr,
                                          const float* __restrict__ poww,
                                          const float* __restrict__ sumsPs,
                                          const float* __restrict__ evec,
                                          const float* __restrict__ avec,
                                          float* __restrict__ memnew,
                                          float* __restrict__ partials,
                                          float* __restrict__ owr,
                                          float* __restrict__ oww) {
    int t = threadIdx.x;  // 256 threads, each owns 4 fixed columns
    int r0 = blockIdx.x * 32;
    __shared__ float swr[32], sww[32];
    if (t < 32) {
        float s = 0.f;
#pragma unroll
        for (int i = 0; i < SLOT_P; i++) s += sumsPs[i * 16];
        swr[t] = powr[r0 + t] * (1.f / (s + 1e-8f));
    } else if (t < 64) {
        float s = 0.f;
#pragma unroll
        for (int i = 0; i < SLOT_P; i++) s += sumsPs[(SLOT_P + i) * 16];
        sww[t - 32] = poww[r0 + t - 32] * (1.f / (s + 1e-8f));
    }
    __syncthreads();
    if (t < 32)      owr[r0 + t] = swr[t];
    else if (t < 64) oww[r0 + t - 32] = sww[t - 32];
    float4 e4 = ((const float4*)evec)[t];
    float4 a4 = ((const float4*)avec)[t];
    float4 acc = make_float4(0.f, 0.f, 0.f, 0.f);
#pragma unroll 4
    for (int rr = 0; rr < 32; rr++) {
        int r = r0 + rr;
        float wr = swr[rr];
        float ww = sww[rr];
        float4 m = ((const float4*)(mem + (size_t)r * COLS))[t];
        vfloat4 o;
        o.x = m.x * (1.f - ww * e4.x) + ww * a4.x;
        o.y = m.y * (1.f - ww * e4.y) + ww * a4.y;
        o.z = m.z * (1.f - ww * e4.z) + ww * a4.z;
        o.w = m.w * (1.f - ww * e4.w) + ww * a4.w;
        __builtin_nontemporal_store(o, ((vfloat4*)(memnew + (size_t)r * COLS)) + t);
        acc.x += wr * m.x;
        acc.y += wr * m.y;
        acc.z += wr * m.z;
        acc.w += wr * m.w;
    }
    ((float4*)(partials + (size_t)blockIdx.x * COLS))[t] = acc;
}

// ---- kH: reduce per-block read_vec partials; one wave per column
__global__ __launch_bounds__(64) void kH(const float* __restrict__ partials,
                                         float* __restrict__ readv) {
    int c = blockIdx.x;          // 0..1023
    int lane = threadIdx.x;      // 0..63
    float s = 0.f;
#pragma unroll
    for (int k = 0; k < NB_G / 64; k++)
        s += partials[(size_t)(lane + 64 * k) * COLS + c];
    s = waveReduceSum(s);
    if (lane == 0) readv[c] = s;
}

extern "C" void kernel_launch(void* const* d_in, const int* in_sizes, int n_in,
                              void* d_out, int out_size, void* d_ws, size_t ws_size,
                              hipStream_t stream) {
    const float* x   = (const float*)d_in[0];
    const float* mem = (const float*)d_in[1];
    const float* Wc  = (const float*)d_in[2];
    const float* bc  = (const float*)d_in[3];
    const float* Wp  = (const float*)d_in[4];
    const float* bp  = (const float*)d_in[5];
    const float* Wo  = (const float*)d_in[6];
    const float* bo  = (const float*)d_in[7];
    const float* rp  = (const float*)d_in[8];
    const float* wrp = (const float*)d_in[9];
    const float* wwp = (const float*)d_in[10];

    float* out    = (float*)d_out;
    float* saida  = out;                                // 256
    float* memnew = out + 256;                          // ROWS*COLS
    float* readv  = out + 256 + (size_t)ROWS * COLS;    // 1024
    float* owr    = readv + COLS;                       // 32768
    float* oww    = owr + ROWS;                         // 32768

    float* ws    = (float*)d_ws;
    float* h     = ws;            // 1024
    float* p     = ws + 1024;     // 4108 (ends 5132, padded)
    float* krn   = ws + 5136;     // 1024
    float* kwn   = ws + 6160;     // 1024
    float* evec  = ws + 7184;     // 1024
    float* avec  = ws + 8208;     // 1024
    float* scal  = ws + 9232;     // 12 (padded to 16)
    float* sumsEs = ws + 9248;    // 2*SLOT_E*16 = 1024 (cache-line-padded slots)
    float* sumsPs = ws + 10272;   // 2*SLOT_P*16 = 512
    float* er    = ws + 10784;    // 32768
    float* ew    = er + ROWS;     // 32768
    float* powr  = ew + ROWS;     // 32768
    float* poww  = powr + ROWS;   // 32768
    float* partials = poww + ROWS;  // NB_G*1024 = 1M floats (4 MB)

    kA<<<dim3(256), dim3(256), 0, stream>>>(x, rp, Wc, bc, h);
    kB<<<dim3(1091), dim3(256), 0, stream>>>(h, Wp, bp, Wo, bo, p, saida);
    kC<<<dim3(1), dim3(1024), 0, stream>>>(p, krn, kwn, evec, avec, scal, sumsEs, sumsPs);
    kD<<<dim3(2048), dim3(256), 0, stream>>>(mem, krn, kwn, scal, er, ew, sumsEs);
    kE<<<dim3(128, 2), dim3(256), 0, stream>>>(er, ew, wrp, wwp, scal, sumsEs, powr, poww, sumsPs);
    kG<<<dim3(NB_G), dim3(256), 0, stream>>>(mem, powr, poww, sumsPs, evec, avec, memnew, partials, owr, oww);
    kH<<<dim3(1024), dim3(64), 0, stream>>>(partials, readv);
}